// Round 12
// baseline (34.941 us; speedup 1.0000x reference)
//
#include <hip/hip_runtime.h>

// LinearAccInterpolation: B x (NKP keyframes) x DIM=2.
// Per segment i (n = idx[i+1]-idx[i]):
//   da = (dy - n*v0 - n(n+1)/2*a0) / (n(n+1)(n+2)/6)
//   pos_k = y0 + k*v0 + k(k+1)/2*a0 + k(k+1)(k+2)/6*da   (k=1..n)
//   v0 += n*a0 + n(n+1)/2*da ;  a0 += n*da
// n<=1: emit y1; a0 = (y1-y0) - v0; v0 = y1-y0.
//
// LESSONS (measured):
//  R6: store coalescing is per WAVE INSTRUCTION => lane l writes base+16l.
//  R7: LDS in a runtime-trip dependent chain = latency-bound.
//  R8/R10: few blocks / serialized phases = latency-bound; TLP is the hider.
//  R11 A/B: nontemporal stores beat plain by 14% on this write stream.
// R12: one-pass, no output LDS. PT=20 thr/batch; thread m (seg=m>>1,h=m&1)
//  runs the FULLY-UNROLLED n=4-reduced recurrence in registers
//  (v' = 0.5dy-v-a ; a' = 0.2dy-0.8v-a), captures its owned segment's
//  (y0,dy,v,a) via branchless selects, computes rows k=1+2h,2+2h, and
//  issues ONE nt 16B store: global f4 index b*20+m == first_b*20+tid.
//  16-batch blocks (320 thr) -> 16384 blocks of TLP, one barrier total.

typedef float f4 __attribute__((ext_vector_type(4)));

template <int NSEG>
__global__ __launch_bounds__(64 * NSEG / 2) void interp_fast(
    const int* __restrict__ index,
    const float2* __restrict__ value,      // B x NKP
    const float2* __restrict__ vinit,      // B x 1
    const float2* __restrict__ ainit,      // B x 1
    float2* __restrict__ out,              // B x rows
    int B, int rows)
{
    constexpr int NKP  = NSEG + 1;
    constexpr int PT   = 2 * NSEG;         // threads per batch (20)
    constexpr int BPB  = 16;               // batches per block
    constexpr int NTHR = BPB * PT;         // 320
    constexpr int NV4  = BPB * NKP / 2;    // 88 f4 of keyframe values
    constexpr int NI4  = BPB / 2;          // 8 f4 per init array

    __shared__ float2 sv[BPB * NKP];
    __shared__ float2 svi[BPB];
    __shared__ float2 sai[BPB];

    int tid = threadIdx.x;
    int first_b = blockIdx.x * BPB;
    int nb = B - first_b;
    if (nb > BPB) nb = BPB;

    // ---- stage inputs (global -> LDS, dense f4) ----
    if (nb == BPB) {
        if (tid < NV4)
            ((f4*)sv)[tid] = ((const f4*)(value + (long)first_b * NKP))[tid];
        else if (tid < NV4 + NI4)
            ((f4*)svi)[tid - NV4] = ((const f4*)(vinit + first_b))[tid - NV4];
        else if (tid < NV4 + 2 * NI4)
            ((f4*)sai)[tid - NV4 - NI4] = ((const f4*)(ainit + first_b))[tid - NV4 - NI4];
    } else {
        for (int f = tid; f < nb * NKP; f += NTHR) sv[f] = value[(long)first_b * NKP + f];
        if (tid < nb) svi[tid] = vinit[first_b + tid];
        else if (tid >= BPB && tid < BPB + nb) sai[tid - BPB] = ainit[first_b + tid - BPB];
    }

    int xi[NKP];
#pragma unroll
    for (int i = 0; i < NKP; ++i) xi[i] = index[i];    // uniform -> scalar

    bool fast = (rows == 4 * NSEG);
#pragma unroll
    for (int i = 0; i < NSEG; ++i) fast = fast && (xi[i + 1] - xi[i] == 4);

    __syncthreads();

    int bl = tid / PT;                     // local batch (magic-mul div)
    int m  = tid - bl * PT;                // 0..PT-1
    if (bl >= nb) return;
    int b = first_b + bl;

    float2 y[NKP];
#pragma unroll
    for (int i = 0; i < NKP; ++i) y[i] = sv[bl * NKP + i];   // broadcast reads
    float2 vv = svi[bl];
    float2 aa = sai[bl];

    if (fast) {                                        // wave-uniform branch
        int iown = m >> 1;                             // owned segment
        int h    = m & 1;                              // rows k=1,2 or 3,4

        float vx = vv.x, vy = vv.y, ax = aa.x, ay = aa.y;
        float yox = 0.f, yoy = 0.f, dyox = 0.f, dyoy = 0.f;
        float vox = 0.f, voy = 0.f, aox = 0.f, aoy = 0.f;
#pragma unroll
        for (int i = 0; i < NSEG; ++i) {
            float dyx = y[i + 1].x - y[i].x;
            float dyy = y[i + 1].y - y[i].y;
            bool own = (i == iown);
            yox  = own ? y[i].x : yox;                 // branchless capture
            yoy  = own ? y[i].y : yoy;
            dyox = own ? dyx : dyox;
            dyoy = own ? dyy : dyoy;
            vox  = own ? vx : vox;
            voy  = own ? vy : voy;
            aox  = own ? ax : aox;
            aoy  = own ? ay : aoy;
            float nvx = 0.5f * dyx - vx - ax;          // n=4-reduced update
            float nvy = 0.5f * dyy - vy - ay;
            ax = 0.2f * dyx - 0.8f * vx - ax;
            ay = 0.2f * dyy - 0.8f * vy - ay;
            vx = nvx; vy = nvy;
        }
        float dax = 0.05f * dyox - 0.2f * vox - 0.5f * aox;
        float day = 0.05f * dyoy - 0.2f * voy - 0.5f * aoy;

        // k=1:(t2,t3)=(1,1) k=2:(3,4) k=3:(6,10) k=4:(10,20)
        float fk1 = h ? 3.0f : 1.0f;
        float fk2 = fk1 + 1.0f;
        float t2a = h ? 6.0f  : 1.0f;
        float t3a = h ? 10.0f : 1.0f;
        float t2b = h ? 10.0f : 3.0f;
        float t3b = h ? 20.0f : 4.0f;

        f4 o;
        o.x = yox + fk1 * vox + t2a * aox + t3a * dax;
        o.y = yoy + fk1 * voy + t2a * aoy + t3a * day;
        o.z = yox + fk2 * vox + t2b * aox + t3b * dax;
        o.w = yoy + fk2 * voy + t2b * aoy + t3b * day;

        // f4 chunk (b*PT + m) == first_b*PT + tid: 1KB contiguous per wave
        __builtin_nontemporal_store(o, (f4*)out + (long)first_b * PT + tid);
    } else {
        // general fallback (not taken for uniform n==4): thread owns global
        // rows [2m, 2m+2); predicated direct float2 stores.
        float2 v0 = vv, a0 = aa;
        int g_lo = 2 * m;
        int g_hi = g_lo + 2;
        if (g_hi > rows) g_hi = rows;
        float2* __restrict__ orow = out + (long)b * rows;
        float2 y0 = y[0];
        int off = 0;
#pragma unroll
        for (int i = 0; i < NSEG; ++i) {
            float2 y1 = y[i + 1];
            int n = xi[i + 1] - xi[i];
            float dyx = y1.x - y0.x;
            float dyy = y1.y - y0.y;
            if (n <= 1) {
                if (off >= g_lo && off < g_hi) orow[off] = y1;
                off += 1;
                a0.x = dyx - v0.x;
                a0.y = dyy - v0.y;
                v0.x = dyx;
                v0.y = dyy;
            } else {
                float fn = (float)n;
                float c1 = fn * (fn + 1.0f) * 0.5f;
                float c2 = fn * (fn + 1.0f) * (fn + 2.0f) / 6.0f;
                float rc2 = __builtin_amdgcn_rcpf(c2);
                float dax = (dyx - fn * v0.x - c1 * a0.x) * rc2;
                float day = (dyy - fn * v0.y - c1 * a0.y) * rc2;
                for (int k = 1; k <= n; ++k) {
                    int g = off + k - 1;
                    if (g >= g_lo && g < g_hi) {
                        float fk = (float)k;
                        float t2 = fk * (fk + 1.0f) * 0.5f;
                        float t3 = fk * (fk + 1.0f) * (fk + 2.0f) * (1.0f / 6.0f);
                        float2 p;
                        p.x = y0.x + fk * v0.x + t2 * a0.x + t3 * dax;
                        p.y = y0.y + fk * v0.y + t2 * a0.y + t3 * day;
                        orow[g] = p;
                    }
                }
                off += n;
                v0.x += fn * a0.x + c1 * dax;
                v0.y += fn * a0.y + c1 * day;
                a0.x += fn * dax;
                a0.y += fn * day;
            }
            y0 = y1;
        }
    }
}

// Runtime-nseg fallback for unexpected nkp/rows: one thread per
// (batch, 8-row chunk), rolling y loads, predicated direct stores.
__global__ __launch_bounds__(256) void interp_gen(
    const int* __restrict__ index,
    const float2* __restrict__ value,
    const float2* __restrict__ vinit,
    const float2* __restrict__ ainit,
    float2* __restrict__ out,
    int B, int nkp, int rows, int PT)
{
    long t = (long)blockIdx.x * 256 + threadIdx.x;
    long total = (long)B * PT;
    if (t >= total) return;
    int b = (int)(t / PT);
    int j = (int)(t - (long)b * PT);
    int g_lo = j * 8;
    int g_hi = g_lo + 8;
    if (g_hi > rows) g_hi = rows;

    const float2* __restrict__ vrow = value + (long)b * nkp;
    float2* __restrict__ orow = out + (long)b * rows;
    float2 v0 = vinit[b];
    float2 a0 = ainit[b];
    float2 y0 = vrow[0];
    int x0 = index[0];
    int off = 0;
    for (int i = 0; i < nkp - 1; ++i) {
        float2 y1 = vrow[i + 1];
        int x1 = index[i + 1];
        int n = x1 - x0; x0 = x1;
        float dyx = y1.x - y0.x, dyy = y1.y - y0.y;
        if (n <= 1) {
            if (off >= g_lo && off < g_hi) orow[off] = y1;
            off += 1;
            a0.x = dyx - v0.x; a0.y = dyy - v0.y;
            v0.x = dyx; v0.y = dyy;
        } else {
            float fn = (float)n;
            float c1 = fn * (fn + 1.0f) * 0.5f;
            float c2 = fn * (fn + 1.0f) * (fn + 2.0f) / 6.0f;
            float dax = (dyx - fn * v0.x - c1 * a0.x) / c2;
            float day = (dyy - fn * v0.y - c1 * a0.y) / c2;
            for (int k = 1; k <= n; ++k) {
                int g = off + k - 1;
                if (g >= g_lo && g < g_hi) {
                    float fk = (float)k;
                    float t2 = fk * (fk + 1.0f) * 0.5f;
                    float t3 = fk * (fk + 1.0f) * (fk + 2.0f) * (1.0f / 6.0f);
                    float2 p;
                    p.x = y0.x + fk * v0.x + t2 * a0.x + t3 * dax;
                    p.y = y0.y + fk * v0.y + t2 * a0.y + t3 * day;
                    orow[g] = p;
                }
            }
            off += n;
            v0.x += fn * a0.x + c1 * dax;
            v0.y += fn * a0.y + c1 * day;
            a0.x += fn * dax;
            a0.y += fn * day;
        }
        y0 = y1;
    }
}

extern "C" void kernel_launch(void* const* d_in, const int* in_sizes, int n_in,
                              void* d_out, int out_size, void* d_ws, size_t ws_size,
                              hipStream_t stream) {
    const int*    index = (const int*)d_in[0];
    const float2* value = (const float2*)d_in[1];
    const float2* vinit = (const float2*)d_in[2];
    const float2* ainit = (const float2*)d_in[3];
    float2*       out   = (float2*)d_out;

    int nkp  = in_sizes[0];                 // 11
    int B    = in_sizes[1] / (nkp * 2);     // 262144
    int rows = out_size / (B * 2);          // 40

    if (nkp == 11 && rows == 40) {
        // 16 batches/block, 20 threads/batch -> 320-thr blocks, 16384 blocks
        dim3 grid((B + 15) / 16);
        interp_fast<10><<<grid, 320, 0, stream>>>(index, value, vinit, ainit, out, B, rows);
    } else {
        int PT = (rows + 7) / 8;
        long total = (long)B * PT;
        dim3 grid((unsigned)((total + 255) / 256));
        interp_gen<<<grid, 256, 0, stream>>>(index, value, vinit, ainit, out, B, nkp, rows, PT);
    }
}

// Round 13
// 22.583 us; speedup vs baseline: 1.5473x; 1.5473x over previous
//
#include <hip/hip_runtime.h>

// LinearAccInterpolation: B x (NKP keyframes) x DIM=2.
// Per segment i (n = idx[i+1]-idx[i]):
//   da = (dy - n*v0 - n(n+1)/2*a0) / (n(n+1)(n+2)/6)
//   pos_k = y0 + k*v0 + k(k+1)/2*a0 + k(k+1)(k+2)/6*da   (k=1..n)
//   v0 += n*a0 + n(n+1)/2*da ;  a0 += n*da
// n<=1: emit y1; a0 = (y1-y0) - v0; v0 = y1-y0.
//
// LESSONS (measured):
//  R6: store coalescing is per WAVE INSTRUCTION => lane l writes base+16l.
//  R7: LDS in a runtime-trip dependent chain = latency-bound.
//  R8/R10: few blocks / long in-block pipelines = latency-bound.
//  R11 A/B: nontemporal stores beat plain by ~14% on this write stream.
//  R12: 20x-redundant recurrence (serial select chain) = 21us VALU, loses.
//  R5 = best (23.9us): 4 lanes/batch, reg recurrence, padded LDS out-tile,
//      burst f4 nt copy-out.
// R13 = R5 with WAVE-LOCAL phases: stage value slab directly into the
//  padded out-tile rows ([bl][0..10] of each 42-f2 row), so wave w owns
//  batches 16w..16w+15 for B1 (reads), B2 (writes rows 0..39, overwriting
//  its own inputs only after reading them), and C (copies chunks
//  320w..320w+319). Same-wave DS ordering makes B1->B2->C safe without
//  barriers; only the post-stage barrier remains (3 barriers -> 1).

typedef float f4 __attribute__((ext_vector_type(4)));

template <int NSEG>
__global__ __launch_bounds__(256) void interp_fast(
    const int* __restrict__ index,
    const float2* __restrict__ value,      // B x NKP
    const float2* __restrict__ vinit,      // B x 1
    const float2* __restrict__ ainit,      // B x 1
    float2* __restrict__ out,              // B x rows (rows = 4*NSEG)
    int B)
{
    constexpr int NKP  = NSEG + 1;         // 11
    constexpr int ROWS = 4 * NSEG;         // 40
    constexpr int PAD2 = ROWS + 2;         // 42 f2 = 336B = 21 f4 per batch
    constexpr int RF4  = ROWS / 2;         // 20 f4 chunks per batch
    constexpr int PF4  = PAD2 / 2;         // 21

    __shared__ float2 lds2[64 * PAD2];     // out tile; input parked in [*][0..10]
    __shared__ float2 svi[64];
    __shared__ float2 sai[64];

    int tid = threadIdx.x;
    int first_b = blockIdx.x * 64;

    // ---- stage (the only barriered phase) ----
    // value slab f2-granular into strided rows: batch bb's keyframes at
    // lds2[bb*PAD2 + 0..10]  (global reads stay dense/coalesced).
    {
        const float2* gv = value + (long)first_b * NKP;
#pragma unroll
        for (int f = tid; f < 64 * NKP; f += 256) {
            int bb = f / NKP;              // const div -> magic mul
            int j  = f - bb * NKP;
            lds2[bb * PAD2 + j] = gv[f];
        }
        if (tid < 32) ((f4*)svi)[tid] = ((const f4*)(vinit + first_b))[tid];
        else if (tid < 64) ((f4*)sai)[tid - 32] = ((const f4*)(ainit + first_b))[tid - 32];
    }

    int xi[NKP];
#pragma unroll
    for (int i = 0; i < NKP; ++i) xi[i] = index[i];    // uniform -> scalar

    bool fast = true;
#pragma unroll
    for (int i = 0; i < NSEG; ++i) fast = fast && (xi[i + 1] - xi[i] == 4);

    __syncthreads();                       // ONE barrier total

    // ---- B1: wave-local LDS -> registers ----
    int bl = tid >> 2;                     // local batch; wave w owns 16w..16w+15
    int r  = tid & 3;                      // lane-in-group
    float2* __restrict__ row = lds2 + bl * PAD2;

    float2 y[NKP];
#pragma unroll
    for (int i = 0; i < NKP; ++i) y[i] = row[i];       // 4-lane broadcast reads
    float2 v0 = svi[bl];
    float2 a0 = sai[bl];

    // ---- B2: recurrence -> own padded row (overwrites own inputs only) ----
    if (fast) {
#pragma unroll
        for (int i = 0; i < NSEG; ++i) {
            float2 y0 = y[i];
            float2 y1 = y[i + 1];
            float dyx = y1.x - y0.x;
            float dyy = y1.y - y0.y;
            // n=4: c1=10, c2=20, 1/c2=0.05
            float dax = (dyx - 4.0f * v0.x - 10.0f * a0.x) * 0.05f;
            float day = (dyy - 4.0f * v0.y - 10.0f * a0.y) * 0.05f;

            // lane r writes row k=r+1 of this segment
            float fk = (float)(r + 1);
            float t2 = fk * (fk + 1.0f) * 0.5f;
            float t3 = t2 * (fk + 2.0f) * (1.0f / 3.0f);
            float2 p;
            p.x = y0.x + fk * v0.x + t2 * a0.x + t3 * dax;
            p.y = y0.y + fk * v0.y + t2 * a0.y + t3 * day;
            row[4 * i + r] = p;

            v0.x += 4.0f * a0.x + 10.0f * dax;
            v0.y += 4.0f * a0.y + 10.0f * day;
            a0.x += 4.0f * dax;
            a0.y += 4.0f * day;
        }
    } else {
        // generic n handling (R5-proven); still wave-local
        int off = 0;
#pragma unroll
        for (int i = 0; i < NSEG; ++i) {
            float2 y0 = y[i];
            float2 y1 = y[i + 1];
            int n = xi[i + 1] - xi[i];
            float dyx = y1.x - y0.x;
            float dyy = y1.y - y0.y;
            if (n <= 1) {
                if (r == 0) row[off] = y1;
                off += 1;
                a0.x = dyx - v0.x;
                a0.y = dyy - v0.y;
                v0.x = dyx;
                v0.y = dyy;
            } else {
                float fn = (float)n;
                float c1 = fn * (fn + 1.0f) * 0.5f;
                float c2 = fn * (fn + 1.0f) * (fn + 2.0f) / 6.0f;
                float rc2 = __builtin_amdgcn_rcpf(c2);
                float dax = (dyx - fn * v0.x - c1 * a0.x) * rc2;
                float day = (dyy - fn * v0.y - c1 * a0.y) * rc2;
                for (int k = r + 1; k <= n; k += 4) {
                    float fk = (float)k;
                    float t2 = fk * (fk + 1.0f) * 0.5f;
                    float t3 = fk * (fk + 1.0f) * (fk + 2.0f) * (1.0f / 6.0f);
                    float2 p;
                    p.x = y0.x + fk * v0.x + t2 * a0.x + t3 * dax;
                    p.y = y0.y + fk * v0.y + t2 * a0.y + t3 * day;
                    if (off + k - 1 < ROWS) row[off + k - 1] = p;
                }
                off += n;
                v0.x += fn * a0.x + c1 * dax;
                v0.y += fn * a0.y + c1 * day;
                a0.x += fn * dax;
                a0.y += fn * day;
            }
        }
    }

    // ---- C: wave-local burst copy-out (no barrier; same-wave DS order) ----
    {
        int w = tid >> 6;                  // wave id 0..3
        int l = tid & 63;
        const f4* __restrict__ l4 = (const f4*)lds2;
        f4* __restrict__ o4 = (f4*)out + (long)first_b * RF4;
        int c0 = w * 16 * RF4;             // 320 chunks per wave
#pragma unroll
        for (int m = 0; m < 16 * RF4 / 64; ++m) {      // 5 iters
            int c  = c0 + m * 64 + l;
            int bb = c / RF4;              // const div -> magic mul
            int j  = c - bb * RF4;
            __builtin_nontemporal_store(l4[bb * PF4 + j], o4 + c);
        }
    }
}

// Runtime fallback for unexpected nkp/rows/B: one thread per (batch, 8-row
// chunk), rolling y loads, predicated direct stores (R11-proven).
__global__ __launch_bounds__(256) void interp_gen(
    const int* __restrict__ index,
    const float2* __restrict__ value,
    const float2* __restrict__ vinit,
    const float2* __restrict__ ainit,
    float2* __restrict__ out,
    int B, int nkp, int rows, int PT)
{
    long t = (long)blockIdx.x * 256 + threadIdx.x;
    long total = (long)B * PT;
    if (t >= total) return;
    int b = (int)(t / PT);
    int j = (int)(t - (long)b * PT);
    int g_lo = j * 8;
    int g_hi = g_lo + 8;
    if (g_hi > rows) g_hi = rows;

    const float2* __restrict__ vrow = value + (long)b * nkp;
    float2* __restrict__ orow = out + (long)b * rows;
    float2 v0 = vinit[b];
    float2 a0 = ainit[b];
    float2 y0 = vrow[0];
    int x0 = index[0];
    int off = 0;
    for (int i = 0; i < nkp - 1; ++i) {
        float2 y1 = vrow[i + 1];
        int x1 = index[i + 1];
        int n = x1 - x0; x0 = x1;
        float dyx = y1.x - y0.x, dyy = y1.y - y0.y;
        if (n <= 1) {
            if (off >= g_lo && off < g_hi) orow[off] = y1;
            off += 1;
            a0.x = dyx - v0.x; a0.y = dyy - v0.y;
            v0.x = dyx; v0.y = dyy;
        } else {
            float fn = (float)n;
            float c1 = fn * (fn + 1.0f) * 0.5f;
            float c2 = fn * (fn + 1.0f) * (fn + 2.0f) / 6.0f;
            float dax = (dyx - fn * v0.x - c1 * a0.x) / c2;
            float day = (dyy - fn * v0.y - c1 * a0.y) / c2;
            for (int k = 1; k <= n; ++k) {
                int g = off + k - 1;
                if (g >= g_lo && g < g_hi) {
                    float fk = (float)k;
                    float t2 = fk * (fk + 1.0f) * 0.5f;
                    float t3 = fk * (fk + 1.0f) * (fk + 2.0f) * (1.0f / 6.0f);
                    float2 p;
                    p.x = y0.x + fk * v0.x + t2 * a0.x + t3 * dax;
                    p.y = y0.y + fk * v0.y + t2 * a0.y + t3 * day;
                    orow[g] = p;
                }
            }
            off += n;
            v0.x += fn * a0.x + c1 * dax;
            v0.y += fn * a0.y + c1 * day;
            a0.x += fn * dax;
            a0.y += fn * day;
        }
        y0 = y1;
    }
}

extern "C" void kernel_launch(void* const* d_in, const int* in_sizes, int n_in,
                              void* d_out, int out_size, void* d_ws, size_t ws_size,
                              hipStream_t stream) {
    const int*    index = (const int*)d_in[0];
    const float2* value = (const float2*)d_in[1];
    const float2* vinit = (const float2*)d_in[2];
    const float2* ainit = (const float2*)d_in[3];
    float2*       out   = (float2*)d_out;

    int nkp  = in_sizes[0];                 // 11
    int B    = in_sizes[1] / (nkp * 2);     // 262144
    int rows = out_size / (B * 2);          // 40

    if (nkp == 11 && rows == 40 && (B % 64) == 0) {
        dim3 grid(B / 64);                  // 4096 blocks of TLP
        interp_fast<10><<<grid, 256, 0, stream>>>(index, value, vinit, ainit, out, B);
    } else {
        int PT = (rows + 7) / 8;
        long total = (long)B * PT;
        dim3 grid((unsigned)((total + 255) / 256));
        interp_gen<<<grid, 256, 0, stream>>>(index, value, vinit, ainit, out, B, nkp, rows, PT);
    }
}

// Round 14
// 21.653 us; speedup vs baseline: 1.6137x; 1.0429x over previous
//
#include <hip/hip_runtime.h>

// LinearAccInterpolation: B x (NKP keyframes) x DIM=2.
// Per segment i (n = idx[i+1]-idx[i]):
//   da = (dy - n*v0 - n(n+1)/2*a0) / (n(n+1)(n+2)/6)
//   pos_k = y0 + k*v0 + k(k+1)/2*a0 + k(k+1)(k+2)/6*da   (k=1..n)
//   v0 += n*a0 + n(n+1)/2*da ;  a0 += n*da
// n<=1: emit y1; a0 = (y1-y0) - v0; v0 = y1-y0.
//
// LESSONS (measured):
//  R6: store coalescing is per WAVE INSTRUCTION => lane l writes base+16l.
//  R7: LDS in a runtime-trip dependent chain = latency-bound.
//  R8/R10: few blocks / long in-block pipelines = latency-bound.
//  R11 A/B: nontemporal stores beat plain by ~14% on this write stream.
//  R12: 20x-redundant recurrence = VALU-chain-bound, loses.
//  R13 (best, 22.6us): wave-local B1/B2/C phases, inputs parked inside the
//      padded out rows, ONE barrier.
// R14 = R13 with ZERO barriers: staging is also wave-local (wave w loads
//  f2 slab indices [176w,176w+176) = its own 16 batches, still 512B-
//  contiguous global reads per wave instruction). Every LDS address is
//  produced and consumed by the same wave -> same-wave DS program order
//  (+ compiler lgkmcnt) is sufficient; the 4 waves run as fully
//  independent pipelines with no rendezvous.

typedef float f4 __attribute__((ext_vector_type(4)));

template <int NSEG>
__global__ __launch_bounds__(256) void interp_fast(
    const int* __restrict__ index,
    const float2* __restrict__ value,      // B x NKP
    const float2* __restrict__ vinit,      // B x 1
    const float2* __restrict__ ainit,      // B x 1
    float2* __restrict__ out,              // B x rows (rows = 4*NSEG)
    int B)
{
    constexpr int NKP  = NSEG + 1;         // 11
    constexpr int ROWS = 4 * NSEG;         // 40
    constexpr int PAD2 = ROWS + 2;         // 42 f2 = 336B = 21 f4 per batch
    constexpr int RF4  = ROWS / 2;         // 20 f4 chunks per batch
    constexpr int PF4  = PAD2 / 2;         // 21
    constexpr int WB   = 16;               // batches per wave
    constexpr int WF2  = WB * NKP;         // 176 f2 of keyframes per wave

    __shared__ float2 lds2[64 * PAD2];     // out tile; inputs parked in [*][0..10]
    __shared__ float2 svi[64];
    __shared__ float2 sai[64];

    int tid = threadIdx.x;
    int w   = tid >> 6;                    // wave 0..3
    int l   = tid & 63;
    int first_b = blockIdx.x * 64;

    // uniform segment lengths (hoisted; scalar loads overlap staging)
    int xi[NKP];
#pragma unroll
    for (int i = 0; i < NKP; ++i) xi[i] = index[i];

    // ---- wave-local staging (NO barrier afterwards) ----
    {
        const float2* gv = value + (long)first_b * NKP;
#pragma unroll
        for (int t = 0; t < (WF2 + 63) / 64; ++t) {
            int fo = t * 64 + l;
            if (fo < WF2) {
                int f  = w * WF2 + fo;
                int bb = f / NKP;          // const div -> magic mul
                int j  = f - bb * NKP;
                lds2[bb * PAD2 + j] = gv[f];
            }
        }
        int wb = w * WB;
        if (l < WB) svi[wb + l] = vinit[first_b + wb + l];
        else if (l < 2 * WB) sai[wb + l - WB] = ainit[first_b + wb + l - WB];
    }

    bool fast = true;
#pragma unroll
    for (int i = 0; i < NSEG; ++i) fast = fast && (xi[i + 1] - xi[i] == 4);

    // ---- B1: wave-local LDS -> registers ----
    int bl = tid >> 2;                     // = 16w + (l>>2): wave-local batch
    int r  = tid & 3;                      // lane-in-group
    float2* __restrict__ row = lds2 + bl * PAD2;

    float2 y[NKP];
#pragma unroll
    for (int i = 0; i < NKP; ++i) y[i] = row[i];       // 4-lane broadcast reads
    float2 v0 = svi[bl];
    float2 a0 = sai[bl];

    // ---- B2: recurrence -> own padded row (overwrites own inputs) ----
    if (fast) {
#pragma unroll
        for (int i = 0; i < NSEG; ++i) {
            float2 y0 = y[i];
            float2 y1 = y[i + 1];
            float dyx = y1.x - y0.x;
            float dyy = y1.y - y0.y;
            // n=4: c1=10, c2=20, 1/c2=0.05
            float dax = (dyx - 4.0f * v0.x - 10.0f * a0.x) * 0.05f;
            float day = (dyy - 4.0f * v0.y - 10.0f * a0.y) * 0.05f;

            float fk = (float)(r + 1);     // lane r writes row k=r+1
            float t2 = fk * (fk + 1.0f) * 0.5f;
            float t3 = t2 * (fk + 2.0f) * (1.0f / 3.0f);
            float2 p;
            p.x = y0.x + fk * v0.x + t2 * a0.x + t3 * dax;
            p.y = y0.y + fk * v0.y + t2 * a0.y + t3 * day;
            row[4 * i + r] = p;

            v0.x += 4.0f * a0.x + 10.0f * dax;
            v0.y += 4.0f * a0.y + 10.0f * day;
            a0.x += 4.0f * dax;
            a0.y += 4.0f * day;
        }
    } else {
        // generic n handling; still wave-local
        int off = 0;
#pragma unroll
        for (int i = 0; i < NSEG; ++i) {
            float2 y0 = y[i];
            float2 y1 = y[i + 1];
            int n = xi[i + 1] - xi[i];
            float dyx = y1.x - y0.x;
            float dyy = y1.y - y0.y;
            if (n <= 1) {
                if (r == 0) row[off] = y1;
                off += 1;
                a0.x = dyx - v0.x;
                a0.y = dyy - v0.y;
                v0.x = dyx;
                v0.y = dyy;
            } else {
                float fn = (float)n;
                float c1 = fn * (fn + 1.0f) * 0.5f;
                float c2 = fn * (fn + 1.0f) * (fn + 2.0f) / 6.0f;
                float rc2 = __builtin_amdgcn_rcpf(c2);
                float dax = (dyx - fn * v0.x - c1 * a0.x) * rc2;
                float day = (dyy - fn * v0.y - c1 * a0.y) * rc2;
                for (int k = r + 1; k <= n; k += 4) {
                    float fk = (float)k;
                    float t2 = fk * (fk + 1.0f) * 0.5f;
                    float t3 = fk * (fk + 1.0f) * (fk + 2.0f) * (1.0f / 6.0f);
                    float2 p;
                    p.x = y0.x + fk * v0.x + t2 * a0.x + t3 * dax;
                    p.y = y0.y + fk * v0.y + t2 * a0.y + t3 * day;
                    if (off + k - 1 < ROWS) row[off + k - 1] = p;
                }
                off += n;
                v0.x += fn * a0.x + c1 * dax;
                v0.y += fn * a0.y + c1 * day;
                a0.x += fn * dax;
                a0.y += fn * day;
            }
        }
    }

    // ---- C: wave-local burst copy-out (same-wave DS order; no barrier) ----
    {
        const f4* __restrict__ l4 = (const f4*)lds2;
        f4* __restrict__ o4 = (f4*)out + (long)first_b * RF4;
        int c0 = w * WB * RF4;             // 320 chunks per wave
#pragma unroll
        for (int m = 0; m < WB * RF4 / 64; ++m) {      // 5 iters
            int c  = c0 + m * 64 + l;
            int bb = c / RF4;              // const div -> magic mul
            int j  = c - bb * RF4;
            __builtin_nontemporal_store(l4[bb * PF4 + j], o4 + c);
        }
    }
}

// Runtime fallback for unexpected nkp/rows/B: one thread per (batch, 8-row
// chunk), rolling y loads, predicated direct stores (R11-proven).
__global__ __launch_bounds__(256) void interp_gen(
    const int* __restrict__ index,
    const float2* __restrict__ value,
    const float2* __restrict__ vinit,
    const float2* __restrict__ ainit,
    float2* __restrict__ out,
    int B, int nkp, int rows, int PT)
{
    long t = (long)blockIdx.x * 256 + threadIdx.x;
    long total = (long)B * PT;
    if (t >= total) return;
    int b = (int)(t / PT);
    int j = (int)(t - (long)b * PT);
    int g_lo = j * 8;
    int g_hi = g_lo + 8;
    if (g_hi > rows) g_hi = rows;

    const float2* __restrict__ vrow = value + (long)b * nkp;
    float2* __restrict__ orow = out + (long)b * rows;
    float2 v0 = vinit[b];
    float2 a0 = ainit[b];
    float2 y0 = vrow[0];
    int x0 = index[0];
    int off = 0;
    for (int i = 0; i < nkp - 1; ++i) {
        float2 y1 = vrow[i + 1];
        int x1 = index[i + 1];
        int n = x1 - x0; x0 = x1;
        float dyx = y1.x - y0.x, dyy = y1.y - y0.y;
        if (n <= 1) {
            if (off >= g_lo && off < g_hi) orow[off] = y1;
            off += 1;
            a0.x = dyx - v0.x; a0.y = dyy - v0.y;
            v0.x = dyx; v0.y = dyy;
        } else {
            float fn = (float)n;
            float c1 = fn * (fn + 1.0f) * 0.5f;
            float c2 = fn * (fn + 1.0f) * (fn + 2.0f) / 6.0f;
            float dax = (dyx - fn * v0.x - c1 * a0.x) / c2;
            float day = (dyy - fn * v0.y - c1 * a0.y) / c2;
            for (int k = 1; k <= n; ++k) {
                int g = off + k - 1;
                if (g >= g_lo && g < g_hi) {
                    float fk = (float)k;
                    float t2 = fk * (fk + 1.0f) * 0.5f;
                    float t3 = fk * (fk + 1.0f) * (fk + 2.0f) * (1.0f / 6.0f);
                    float2 p;
                    p.x = y0.x + fk * v0.x + t2 * a0.x + t3 * dax;
                    p.y = y0.y + fk * v0.y + t2 * a0.y + t3 * day;
                    orow[g] = p;
                }
            }
            off += n;
            v0.x += fn * a0.x + c1 * dax;
            v0.y += fn * a0.y + c1 * day;
            a0.x += fn * dax;
            a0.y += fn * day;
        }
        y0 = y1;
    }
}

extern "C" void kernel_launch(void* const* d_in, const int* in_sizes, int n_in,
                              void* d_out, int out_size, void* d_ws, size_t ws_size,
                              hipStream_t stream) {
    const int*    index = (const int*)d_in[0];
    const float2* value = (const float2*)d_in[1];
    const float2* vinit = (const float2*)d_in[2];
    const float2* ainit = (const float2*)d_in[3];
    float2*       out   = (float2*)d_out;

    int nkp  = in_sizes[0];                 // 11
    int B    = in_sizes[1] / (nkp * 2);     // 262144
    int rows = out_size / (B * 2);          // 40

    if (nkp == 11 && rows == 40 && (B % 64) == 0) {
        dim3 grid(B / 64);                  // 4096 blocks of TLP
        interp_fast<10><<<grid, 256, 0, stream>>>(index, value, vinit, ainit, out, B);
    } else {
        int PT = (rows + 7) / 8;
        long total = (long)B * PT;
        dim3 grid((unsigned)((total + 255) / 256));
        interp_gen<<<grid, 256, 0, stream>>>(index, value, vinit, ainit, out, B, nkp, rows, PT);
    }
}